// Round 2
// baseline (328.994 us; speedup 1.0000x reference)
//
#include <hip/hip_runtime.h>

#define K 8

__global__ __launch_bounds__(256) void shade_blend_kernel(
    const float* __restrict__ bary,   // [P,K,3]
    const float* __restrict__ zbuf,   // [P,K]
    const float* __restrict__ dists,  // [P,K]
    const float* __restrict__ vn,     // [V,3]
    const int*   __restrict__ p2f,    // [P,K]
    const int*   __restrict__ faces,  // [F,3]
    float* __restrict__ out,          // [P,4]
    int P)
{
    const float SIGMA_INV = 1e4f;    // 1/1e-4
    const float GAMMA_INV = 1e4f;    // 1/1e-4
    const float EPSV      = 1e-10f;
    const float ZFAR      = 100.0f;
    const float ZSCALE    = 1.0f / 99.0f;   // 1/(ZFAR-ZNEAR)

    int pix = blockIdx.x * blockDim.x + threadIdx.x;
    if (pix >= P) return;

    // ---- vectorized loads of the per-pixel streams ----
    const float4* zb4 = reinterpret_cast<const float4*>(zbuf  + (size_t)pix * K);
    const float4* ds4 = reinterpret_cast<const float4*>(dists + (size_t)pix * K);
    const int4*   pf4 = reinterpret_cast<const int4*>(p2f     + (size_t)pix * K);
    const float4* bc4 = reinterpret_cast<const float4*>(bary  + (size_t)pix * K * 3);

    float4 za = zb4[0], zb_ = zb4[1];
    float4 da = ds4[0], db_ = ds4[1];
    int4   fa = pf4[0], fb_ = pf4[1];

    float zk[K] = { za.x, za.y, za.z, za.w, zb_.x, zb_.y, zb_.z, zb_.w };
    float dk[K] = { da.x, da.y, da.z, da.w, db_.x, db_.y, db_.z, db_.w };
    int   fk[K] = { fa.x, fa.y, fa.z, fa.w, fb_.x, fb_.y, fb_.z, fb_.w };

    float barr[K * 3];
#pragma unroll
    for (int i = 0; i < 6; ++i) {
        float4 t = bc4[i];
        barr[4 * i + 0] = t.x;
        barr[4 * i + 1] = t.y;
        barr[4 * i + 2] = t.z;
        barr[4 * i + 3] = t.w;
    }

    // ---- per-fragment shading + softmax pre-pass ----
    float prob[K], zinv[K], c0[K], c1[K], c2[K];
    float zmax = EPSV;

#pragma unroll
    for (int k = 0; k < K; ++k) {
        bool m = fk[k] >= 0;
        // sigmoid(-d/sigma) = 1 / (1 + exp(d/sigma))
        float p = 1.0f / (1.0f + __expf(dk[k] * SIGMA_INV));
        prob[k] = m ? p : 0.0f;
        float zi = (ZFAR - zk[k]) * ZSCALE;
        zinv[k] = m ? zi : 0.0f;
        zmax = fmaxf(zmax, zinv[k]);

        if (m) {
            int fi = fk[k];
            int v0 = faces[3 * fi + 0];
            int v1 = faces[3 * fi + 1];
            int v2 = faces[3 * fi + 2];
            float b0 = barr[3 * k + 0];
            float b1 = barr[3 * k + 1];
            float b2 = barr[3 * k + 2];
            float n0x = vn[3 * v0 + 0], n0y = vn[3 * v0 + 1], n0z = vn[3 * v0 + 2];
            float n1x = vn[3 * v1 + 0], n1y = vn[3 * v1 + 1], n1z = vn[3 * v1 + 2];
            float n2x = vn[3 * v2 + 0], n2y = vn[3 * v2 + 1], n2z = vn[3 * v2 + 2];
            c0[k] = b0 * n0x + b1 * n1x + b2 * n2x;
            c1[k] = b0 * n0y + b1 * n1y + b2 * n2y;
            c2[k] = b0 * n0z + b1 * n1z + b2 * n2z;
        } else {
            c0[k] = 0.0f; c1[k] = 0.0f; c2[k] = 0.0f;
        }
    }

    // ---- blend ----
    float one_minus_prod = 1.0f;
    float wsum = 0.0f, a0 = 0.0f, a1 = 0.0f, a2 = 0.0f;
#pragma unroll
    for (int k = 0; k < K; ++k) {
        one_minus_prod *= (1.0f - prob[k]);
        float w = prob[k] * __expf((zinv[k] - zmax) * GAMMA_INV);
        wsum += w;
        a0 += w * c0[k];
        a1 += w * c1[k];
        a2 += w * c2[k];
    }
    float delta = __expf((EPSV - zmax) * GAMMA_INV);
    float inv_denom = 1.0f / (wsum + delta);
    float bgw = delta * inv_denom;   // background = (1,1,1)

    float4 o;
    o.x = a0 * inv_denom + bgw;
    o.y = a1 * inv_denom + bgw;
    o.z = a2 * inv_denom + bgw;
    o.w = 1.0f - one_minus_prod;
    *reinterpret_cast<float4*>(out + (size_t)pix * 4) = o;
}

extern "C" void kernel_launch(void* const* d_in, const int* in_sizes, int n_in,
                              void* d_out, int out_size, void* d_ws, size_t ws_size,
                              hipStream_t stream) {
    const float* bary  = (const float*)d_in[0];
    const float* zbuf  = (const float*)d_in[1];
    const float* dists = (const float*)d_in[2];
    const float* vn    = (const float*)d_in[3];
    const int*   p2f   = (const int*)d_in[4];
    const int*   faces = (const int*)d_in[5];
    float* out = (float*)d_out;

    int P = out_size / 4;              // N*H*W pixels
    int block = 256;
    int grid = (P + block - 1) / block;
    shade_blend_kernel<<<grid, block, 0, stream>>>(bary, zbuf, dists, vn, p2f, faces, out, P);
}

// Round 3
// 304.570 us; speedup vs baseline: 1.0802x; 1.0802x over previous
//
#include <hip/hip_runtime.h>
#include <hip/hip_fp16.h>

#define K 8

static __device__ __forceinline__ unsigned pack2(float lo, float hi) {
    __half2 h = __floats2half2_rn(lo, hi);
    return *reinterpret_cast<unsigned*>(&h);
}
static __device__ __forceinline__ float2 unpack2(unsigned u) {
    __half2 h = *reinterpret_cast<__half2*>(&u);
    return __half22float2(h);
}

// ---- pass 1: pack faces -> per-face vertex-normal table (fp16, 32B records) ----
__global__ __launch_bounds__(256) void pack_face_normals(
    const int*   __restrict__ faces,  // [F,3]
    const float* __restrict__ vn,     // [V,3]
    uint4*       __restrict__ tbl,    // [F*2] (32 B per face)
    int F)
{
    int f = blockIdx.x * blockDim.x + threadIdx.x;
    if (f >= F) return;
    int v0 = faces[3 * f + 0];
    int v1 = faces[3 * f + 1];
    int v2 = faces[3 * f + 2];
    float n0x = vn[3 * v0 + 0], n0y = vn[3 * v0 + 1], n0z = vn[3 * v0 + 2];
    float n1x = vn[3 * v1 + 0], n1y = vn[3 * v1 + 1], n1z = vn[3 * v1 + 2];
    float n2x = vn[3 * v2 + 0], n2y = vn[3 * v2 + 1], n2z = vn[3 * v2 + 2];
    uint4 a, b;
    a.x = pack2(n0x, n0y);
    a.y = pack2(n0z, n1x);
    a.z = pack2(n1y, n1z);
    a.w = pack2(n2x, n2y);
    b.x = pack2(n2z, 0.0f);
    b.y = 0u; b.z = 0u; b.w = 0u;
    tbl[2 * f + 0] = a;
    tbl[2 * f + 1] = b;
}

// ---- pass 2: shade + softmax blend, single-level gather into packed table ----
__global__ __launch_bounds__(256) void shade_blend_packed(
    const float*    __restrict__ bary,   // [P,K,3]
    const float*    __restrict__ zbuf,   // [P,K]
    const float*    __restrict__ dists,  // [P,K]
    const int*      __restrict__ p2f,    // [P,K]
    const uint4*    __restrict__ tbl,    // [F*2]
    float*          __restrict__ out,    // [P,4]
    int P)
{
    const float SIGMA_INV = 1e4f;
    const float GAMMA_INV = 1e4f;
    const float EPSV      = 1e-10f;
    const float ZFAR      = 100.0f;
    const float ZSCALE    = 1.0f / 99.0f;

    int pix = blockIdx.x * blockDim.x + threadIdx.x;
    if (pix >= P) return;

    const float4* zb4 = reinterpret_cast<const float4*>(zbuf  + (size_t)pix * K);
    const float4* ds4 = reinterpret_cast<const float4*>(dists + (size_t)pix * K);
    const int4*   pf4 = reinterpret_cast<const int4*>(p2f     + (size_t)pix * K);
    const float4* bc4 = reinterpret_cast<const float4*>(bary  + (size_t)pix * K * 3);
    const unsigned* tbl32 = reinterpret_cast<const unsigned*>(tbl);

    float4 za = zb4[0], zb_ = zb4[1];
    float4 da = ds4[0], db_ = ds4[1];
    int4   fa = pf4[0], fb_ = pf4[1];

    float zk[K] = { za.x, za.y, za.z, za.w, zb_.x, zb_.y, zb_.z, zb_.w };
    float dk[K] = { da.x, da.y, da.z, da.w, db_.x, db_.y, db_.z, db_.w };
    int   fk[K] = { fa.x, fa.y, fa.z, fa.w, fb_.x, fb_.y, fb_.z, fb_.w };

    float barr[K * 3];
#pragma unroll
    for (int i = 0; i < 6; ++i) {
        float4 t = bc4[i];
        barr[4 * i + 0] = t.x;
        barr[4 * i + 1] = t.y;
        barr[4 * i + 2] = t.z;
        barr[4 * i + 3] = t.w;
    }

    float prob[K], zinv[K], c0[K], c1[K], c2[K];
    float zmax = EPSV;

#pragma unroll
    for (int k = 0; k < K; ++k) {
        int fraw = fk[k];
        float mf = fraw >= 0 ? 1.0f : 0.0f;
        int fi = fraw >= 0 ? fraw : 0;

        // branchless gather: one 32B record = one 64B-line fetch
        uint4    ra = tbl[2 * fi];
        unsigned rb = tbl32[8 * fi + 4];

        float p = 1.0f / (1.0f + __expf(dk[k] * SIGMA_INV));
        prob[k] = p * mf;
        zinv[k] = (ZFAR - zk[k]) * ZSCALE * mf;
        zmax = fmaxf(zmax, zinv[k]);

        float2 p01 = unpack2(ra.x);   // n0x n0y
        float2 p23 = unpack2(ra.y);   // n0z n1x
        float2 p45 = unpack2(ra.z);   // n1y n1z
        float2 p67 = unpack2(ra.w);   // n2x n2y
        float2 p8  = unpack2(rb);     // n2z -
        float b0 = barr[3 * k + 0] * mf;
        float b1 = barr[3 * k + 1] * mf;
        float b2 = barr[3 * k + 2] * mf;
        c0[k] = b0 * p01.x + b1 * p23.y + b2 * p67.x;
        c1[k] = b0 * p01.y + b1 * p45.x + b2 * p67.y;
        c2[k] = b0 * p23.x + b1 * p45.y + b2 * p8.x;
    }

    float one_minus_prod = 1.0f;
    float wsum = 0.0f, a0 = 0.0f, a1 = 0.0f, a2 = 0.0f;
#pragma unroll
    for (int k = 0; k < K; ++k) {
        one_minus_prod *= (1.0f - prob[k]);
        float w = prob[k] * __expf((zinv[k] - zmax) * GAMMA_INV);
        wsum += w;
        a0 += w * c0[k];
        a1 += w * c1[k];
        a2 += w * c2[k];
    }
    float delta = __expf((EPSV - zmax) * GAMMA_INV);
    float inv_denom = 1.0f / (wsum + delta);
    float bgw = delta * inv_denom;

    float4 o;
    o.x = a0 * inv_denom + bgw;
    o.y = a1 * inv_denom + bgw;
    o.z = a2 * inv_denom + bgw;
    o.w = 1.0f - one_minus_prod;
    *reinterpret_cast<float4*>(out + (size_t)pix * 4) = o;
}

// ---- fallback (no workspace): original two-level gather ----
__global__ __launch_bounds__(256) void shade_blend_direct(
    const float* __restrict__ bary, const float* __restrict__ zbuf,
    const float* __restrict__ dists, const float* __restrict__ vn,
    const int* __restrict__ p2f, const int* __restrict__ faces,
    float* __restrict__ out, int P)
{
    const float SIGMA_INV = 1e4f, GAMMA_INV = 1e4f, EPSV = 1e-10f;
    const float ZFAR = 100.0f, ZSCALE = 1.0f / 99.0f;
    int pix = blockIdx.x * blockDim.x + threadIdx.x;
    if (pix >= P) return;
    const float4* zb4 = reinterpret_cast<const float4*>(zbuf  + (size_t)pix * K);
    const float4* ds4 = reinterpret_cast<const float4*>(dists + (size_t)pix * K);
    const int4*   pf4 = reinterpret_cast<const int4*>(p2f     + (size_t)pix * K);
    const float4* bc4 = reinterpret_cast<const float4*>(bary  + (size_t)pix * K * 3);
    float4 za = zb4[0], zb_ = zb4[1];
    float4 da = ds4[0], db_ = ds4[1];
    int4   fa = pf4[0], fb_ = pf4[1];
    float zk[K] = { za.x, za.y, za.z, za.w, zb_.x, zb_.y, zb_.z, zb_.w };
    float dk[K] = { da.x, da.y, da.z, da.w, db_.x, db_.y, db_.z, db_.w };
    int   fk[K] = { fa.x, fa.y, fa.z, fa.w, fb_.x, fb_.y, fb_.z, fb_.w };
    float barr[K * 3];
#pragma unroll
    for (int i = 0; i < 6; ++i) {
        float4 t = bc4[i];
        barr[4 * i + 0] = t.x; barr[4 * i + 1] = t.y;
        barr[4 * i + 2] = t.z; barr[4 * i + 3] = t.w;
    }
    float prob[K], zinv[K], c0[K], c1[K], c2[K];
    float zmax = EPSV;
#pragma unroll
    for (int k = 0; k < K; ++k) {
        int fraw = fk[k];
        float mf = fraw >= 0 ? 1.0f : 0.0f;
        int fi = fraw >= 0 ? fraw : 0;
        int v0 = faces[3 * fi + 0], v1 = faces[3 * fi + 1], v2 = faces[3 * fi + 2];
        float p = 1.0f / (1.0f + __expf(dk[k] * SIGMA_INV));
        prob[k] = p * mf;
        zinv[k] = (ZFAR - zk[k]) * ZSCALE * mf;
        zmax = fmaxf(zmax, zinv[k]);
        float b0 = barr[3 * k + 0] * mf, b1 = barr[3 * k + 1] * mf, b2 = barr[3 * k + 2] * mf;
        c0[k] = b0 * vn[3 * v0 + 0] + b1 * vn[3 * v1 + 0] + b2 * vn[3 * v2 + 0];
        c1[k] = b0 * vn[3 * v0 + 1] + b1 * vn[3 * v1 + 1] + b2 * vn[3 * v2 + 1];
        c2[k] = b0 * vn[3 * v0 + 2] + b1 * vn[3 * v1 + 2] + b2 * vn[3 * v2 + 2];
    }
    float one_minus_prod = 1.0f, wsum = 0.0f, a0 = 0.0f, a1 = 0.0f, a2 = 0.0f;
#pragma unroll
    for (int k = 0; k < K; ++k) {
        one_minus_prod *= (1.0f - prob[k]);
        float w = prob[k] * __expf((zinv[k] - zmax) * GAMMA_INV);
        wsum += w; a0 += w * c0[k]; a1 += w * c1[k]; a2 += w * c2[k];
    }
    float delta = __expf((EPSV - zmax) * GAMMA_INV);
    float inv_denom = 1.0f / (wsum + delta);
    float bgw = delta * inv_denom;
    float4 o;
    o.x = a0 * inv_denom + bgw; o.y = a1 * inv_denom + bgw;
    o.z = a2 * inv_denom + bgw; o.w = 1.0f - one_minus_prod;
    *reinterpret_cast<float4*>(out + (size_t)pix * 4) = o;
}

extern "C" void kernel_launch(void* const* d_in, const int* in_sizes, int n_in,
                              void* d_out, int out_size, void* d_ws, size_t ws_size,
                              hipStream_t stream) {
    const float* bary  = (const float*)d_in[0];
    const float* zbuf  = (const float*)d_in[1];
    const float* dists = (const float*)d_in[2];
    const float* vn    = (const float*)d_in[3];
    const int*   p2f   = (const int*)d_in[4];
    const int*   faces = (const int*)d_in[5];
    float* out = (float*)d_out;

    int P = out_size / 4;           // N*H*W pixels
    int F = in_sizes[5] / 3;        // faces
    int block = 256;
    int grid = (P + block - 1) / block;

    size_t tbl_bytes = (size_t)F * 32;
    if (ws_size >= tbl_bytes) {
        uint4* tbl = (uint4*)d_ws;
        int gf = (F + block - 1) / block;
        pack_face_normals<<<gf, block, 0, stream>>>(faces, vn, tbl, F);
        shade_blend_packed<<<grid, block, 0, stream>>>(bary, zbuf, dists, p2f, tbl, out, P);
    } else {
        shade_blend_direct<<<grid, block, 0, stream>>>(bary, zbuf, dists, vn, p2f, faces, out, P);
    }
}

// Round 4
// 279.100 us; speedup vs baseline: 1.1788x; 1.0913x over previous
//
#include <hip/hip_runtime.h>

#define K 8

typedef float    f32x4 __attribute__((ext_vector_type(4)));
typedef int      i32x4 __attribute__((ext_vector_type(4)));
typedef unsigned u32x4 __attribute__((ext_vector_type(4)));

static __device__ __forceinline__ unsigned quant10(float v) {
    v = fminf(fmaxf(v, -1.0f), 1.0f);
    return (unsigned)__float2uint_rn((v + 1.0f) * 511.5f);   // [0,1023]
}

// ---- pass 1: faces + vn -> per-face quantized normal table (16 B/face) ----
// word0 = n0x | n0y<<10 | n0z<<20 ; word1 = n1 ; word2 = n2 ; word3 = 0
__global__ __launch_bounds__(256) void pack_face_normals_q10(
    const int*   __restrict__ faces,  // [F,3]
    const float* __restrict__ vn,     // [V,3]
    u32x4*       __restrict__ tbl,    // [F]
    int F)
{
    int f = blockIdx.x * blockDim.x + threadIdx.x;
    if (f >= F) return;
    int v0 = faces[3 * f + 0];
    int v1 = faces[3 * f + 1];
    int v2 = faces[3 * f + 2];
    u32x4 r;
    r.x = quant10(vn[3 * v0 + 0]) | (quant10(vn[3 * v0 + 1]) << 10) | (quant10(vn[3 * v0 + 2]) << 20);
    r.y = quant10(vn[3 * v1 + 0]) | (quant10(vn[3 * v1 + 1]) << 10) | (quant10(vn[3 * v1 + 2]) << 20);
    r.z = quant10(vn[3 * v2 + 0]) | (quant10(vn[3 * v2 + 1]) << 10) | (quant10(vn[3 * v2 + 2]) << 20);
    r.w = 0u;
    tbl[f] = r;
}

static __device__ __forceinline__ float dq(unsigned w, int shift) {
    const float S = 2.0f / 1023.0f;
    return (float)((w >> shift) & 1023u) * S - 1.0f;
}

// ---- pass 2: shade + softmax blend; nt streams, single dwordx4 gather ----
__global__ __launch_bounds__(256) void shade_blend_q10(
    const float* __restrict__ bary,   // [P,K,3]
    const float* __restrict__ zbuf,   // [P,K]
    const float* __restrict__ dists,  // [P,K]
    const int*   __restrict__ p2f,    // [P,K]
    const u32x4* __restrict__ tbl,    // [F]
    float*       __restrict__ out,    // [P,4]
    int P)
{
    const float SIGMA_INV = 1e4f;
    const float GAMMA_INV = 1e4f;
    const float EPSV      = 1e-10f;
    const float ZFAR      = 100.0f;
    const float ZSCALE    = 1.0f / 99.0f;

    int pix = blockIdx.x * blockDim.x + threadIdx.x;
    if (pix >= P) return;

    const f32x4* zb4 = reinterpret_cast<const f32x4*>(zbuf  + (size_t)pix * K);
    const f32x4* ds4 = reinterpret_cast<const f32x4*>(dists + (size_t)pix * K);
    const i32x4* pf4 = reinterpret_cast<const i32x4*>(p2f   + (size_t)pix * K);
    const f32x4* bc4 = reinterpret_cast<const f32x4*>(bary  + (size_t)pix * K * 3);

    // non-temporal streaming loads (don't evict the gather table)
    f32x4 za  = __builtin_nontemporal_load(zb4 + 0);
    f32x4 zb_ = __builtin_nontemporal_load(zb4 + 1);
    f32x4 da  = __builtin_nontemporal_load(ds4 + 0);
    f32x4 db_ = __builtin_nontemporal_load(ds4 + 1);
    i32x4 fa  = __builtin_nontemporal_load(pf4 + 0);
    i32x4 fb_ = __builtin_nontemporal_load(pf4 + 1);

    float zk[K] = { za.x, za.y, za.z, za.w, zb_.x, zb_.y, zb_.z, zb_.w };
    float dk[K] = { da.x, da.y, da.z, da.w, db_.x, db_.y, db_.z, db_.w };
    int   fk[K] = { fa.x, fa.y, fa.z, fa.w, fb_.x, fb_.y, fb_.z, fb_.w };

    float barr[K * 3];
#pragma unroll
    for (int i = 0; i < 6; ++i) {
        f32x4 t = __builtin_nontemporal_load(bc4 + i);
        barr[4 * i + 0] = t.x;
        barr[4 * i + 1] = t.y;
        barr[4 * i + 2] = t.z;
        barr[4 * i + 3] = t.w;
    }

    // issue all gathers up front (independent, overlapped)
    u32x4 rec[K];
#pragma unroll
    for (int k = 0; k < K; ++k) {
        int fi = fk[k] >= 0 ? fk[k] : 0;
        rec[k] = tbl[fi];                 // single 16 B scattered load
    }

    float prob[K], zinv[K], c0[K], c1[K], c2[K];
    float zmax = EPSV;

#pragma unroll
    for (int k = 0; k < K; ++k) {
        float mf = fk[k] >= 0 ? 1.0f : 0.0f;

        float p = 1.0f / (1.0f + __expf(dk[k] * SIGMA_INV));
        prob[k] = p * mf;
        zinv[k] = (ZFAR - zk[k]) * ZSCALE * mf;
        zmax = fmaxf(zmax, zinv[k]);

        unsigned w0 = rec[k].x, w1 = rec[k].y, w2 = rec[k].z;
        float b0 = barr[3 * k + 0] * mf;
        float b1 = barr[3 * k + 1] * mf;
        float b2 = barr[3 * k + 2] * mf;
        c0[k] = b0 * dq(w0, 0)  + b1 * dq(w1, 0)  + b2 * dq(w2, 0);
        c1[k] = b0 * dq(w0, 10) + b1 * dq(w1, 10) + b2 * dq(w2, 10);
        c2[k] = b0 * dq(w0, 20) + b1 * dq(w1, 20) + b2 * dq(w2, 20);
    }

    float one_minus_prod = 1.0f;
    float wsum = 0.0f, a0 = 0.0f, a1 = 0.0f, a2 = 0.0f;
#pragma unroll
    for (int k = 0; k < K; ++k) {
        one_minus_prod *= (1.0f - prob[k]);
        float w = prob[k] * __expf((zinv[k] - zmax) * GAMMA_INV);
        wsum += w;
        a0 += w * c0[k];
        a1 += w * c1[k];
        a2 += w * c2[k];
    }
    float delta = __expf((EPSV - zmax) * GAMMA_INV);
    float inv_denom = 1.0f / (wsum + delta);
    float bgw = delta * inv_denom;   // background = (1,1,1)

    f32x4 o;
    o.x = a0 * inv_denom + bgw;
    o.y = a1 * inv_denom + bgw;
    o.z = a2 * inv_denom + bgw;
    o.w = 1.0f - one_minus_prod;
    __builtin_nontemporal_store(o, reinterpret_cast<f32x4*>(out + (size_t)pix * 4));
}

// ---- fallback (workspace too small): two-level gather ----
__global__ __launch_bounds__(256) void shade_blend_direct(
    const float* __restrict__ bary, const float* __restrict__ zbuf,
    const float* __restrict__ dists, const float* __restrict__ vn,
    const int* __restrict__ p2f, const int* __restrict__ faces,
    float* __restrict__ out, int P)
{
    const float SIGMA_INV = 1e4f, GAMMA_INV = 1e4f, EPSV = 1e-10f;
    const float ZFAR = 100.0f, ZSCALE = 1.0f / 99.0f;
    int pix = blockIdx.x * blockDim.x + threadIdx.x;
    if (pix >= P) return;
    const float4* zb4 = reinterpret_cast<const float4*>(zbuf  + (size_t)pix * K);
    const float4* ds4 = reinterpret_cast<const float4*>(dists + (size_t)pix * K);
    const int4*   pf4 = reinterpret_cast<const int4*>(p2f     + (size_t)pix * K);
    const float4* bc4 = reinterpret_cast<const float4*>(bary  + (size_t)pix * K * 3);
    float4 za = zb4[0], zb_ = zb4[1];
    float4 da = ds4[0], db_ = ds4[1];
    int4   fa = pf4[0], fb_ = pf4[1];
    float zk[K] = { za.x, za.y, za.z, za.w, zb_.x, zb_.y, zb_.z, zb_.w };
    float dk[K] = { da.x, da.y, da.z, da.w, db_.x, db_.y, db_.z, db_.w };
    int   fk[K] = { fa.x, fa.y, fa.z, fa.w, fb_.x, fb_.y, fb_.z, fb_.w };
    float barr[K * 3];
#pragma unroll
    for (int i = 0; i < 6; ++i) {
        float4 t = bc4[i];
        barr[4 * i + 0] = t.x; barr[4 * i + 1] = t.y;
        barr[4 * i + 2] = t.z; barr[4 * i + 3] = t.w;
    }
    float prob[K], zinv[K], c0[K], c1[K], c2[K];
    float zmax = EPSV;
#pragma unroll
    for (int k = 0; k < K; ++k) {
        int fraw = fk[k];
        float mf = fraw >= 0 ? 1.0f : 0.0f;
        int fi = fraw >= 0 ? fraw : 0;
        int v0 = faces[3 * fi + 0], v1 = faces[3 * fi + 1], v2 = faces[3 * fi + 2];
        float p = 1.0f / (1.0f + __expf(dk[k] * SIGMA_INV));
        prob[k] = p * mf;
        zinv[k] = (ZFAR - zk[k]) * ZSCALE * mf;
        zmax = fmaxf(zmax, zinv[k]);
        float b0 = barr[3 * k + 0] * mf, b1 = barr[3 * k + 1] * mf, b2 = barr[3 * k + 2] * mf;
        c0[k] = b0 * vn[3 * v0 + 0] + b1 * vn[3 * v1 + 0] + b2 * vn[3 * v2 + 0];
        c1[k] = b0 * vn[3 * v0 + 1] + b1 * vn[3 * v1 + 1] + b2 * vn[3 * v2 + 1];
        c2[k] = b0 * vn[3 * v0 + 2] + b1 * vn[3 * v1 + 2] + b2 * vn[3 * v2 + 2];
    }
    float one_minus_prod = 1.0f, wsum = 0.0f, a0 = 0.0f, a1 = 0.0f, a2 = 0.0f;
#pragma unroll
    for (int k = 0; k < K; ++k) {
        one_minus_prod *= (1.0f - prob[k]);
        float w = prob[k] * __expf((zinv[k] - zmax) * GAMMA_INV);
        wsum += w; a0 += w * c0[k]; a1 += w * c1[k]; a2 += w * c2[k];
    }
    float delta = __expf((EPSV - zmax) * GAMMA_INV);
    float inv_denom = 1.0f / (wsum + delta);
    float bgw = delta * inv_denom;
    float4 o;
    o.x = a0 * inv_denom + bgw; o.y = a1 * inv_denom + bgw;
    o.z = a2 * inv_denom + bgw; o.w = 1.0f - one_minus_prod;
    *reinterpret_cast<float4*>(out + (size_t)pix * 4) = o;
}

extern "C" void kernel_launch(void* const* d_in, const int* in_sizes, int n_in,
                              void* d_out, int out_size, void* d_ws, size_t ws_size,
                              hipStream_t stream) {
    const float* bary  = (const float*)d_in[0];
    const float* zbuf  = (const float*)d_in[1];
    const float* dists = (const float*)d_in[2];
    const float* vn    = (const float*)d_in[3];
    const int*   p2f   = (const int*)d_in[4];
    const int*   faces = (const int*)d_in[5];
    float* out = (float*)d_out;

    int P = out_size / 4;           // N*H*W pixels
    int F = in_sizes[5] / 3;        // faces
    int block = 256;
    int grid = (P + block - 1) / block;

    size_t tbl_bytes = (size_t)F * 16;
    if (ws_size >= tbl_bytes) {
        u32x4* tbl = (u32x4*)d_ws;
        int gf = (F + block - 1) / block;
        pack_face_normals_q10<<<gf, block, 0, stream>>>(faces, vn, tbl, F);
        shade_blend_q10<<<grid, block, 0, stream>>>(bary, zbuf, dists, p2f, tbl, out, P);
    } else {
        shade_blend_direct<<<grid, block, 0, stream>>>(bary, zbuf, dists, vn, p2f, faces, out, P);
    }
}